// Round 8
// baseline (124.285 us; speedup 1.0000x reference)
//
#include <hip/hip_runtime.h>
#include <stdint.h>

// Soft decision-tree ensemble, collapsed to:
//   out[b,c] = sum_t ( A'[t,c] + sum_{k<4} d[b,t,k]*B'[t,k,c] ) / (4 + d[b,t,3] + 1e-8)
//   d[b,t,k] = sigmoid( X[b,:] . W[t,k,:] + bias[t,k] ),  nodes 0..3 only.
// GEMM 65536x512 @ 512x256, memory-bound on X (134 MB fp32 read once).
// R8: ZERO barriers in the K-loop. Block = 32 rows; X staged ONCE for full
// K=512 (f16, 32 KB LDS, XOR-granule swizzle), one __syncthreads, then the
// K-loop free-runs from read-only LDS. W streams global->reg (L1/L2-hot).
// 4 blocks/CU x 4 waves: staging of one block overlaps compute of others
// (TLP latency hiding, fillBuffer-style — no lockstep, no vmcnt gymnastics).

#define KDIM 512
#define PPT 3607

typedef _Float16 f16x8 __attribute__((ext_vector_type(8)));
typedef float f32x4 __attribute__((ext_vector_type(4)));

// ws layout (bytes):
//   [0, 262144)       Wh   : _Float16 [256 cols][512 k]   (col = t*4 + node)
//   [262144, 263168)  biasN: float[256]
//   [263168, 265728)  AB   : float[64][10]

__global__ __launch_bounds__(128) void prep_kernel(const float* __restrict__ p,
                                                   const float* __restrict__ tw,
                                                   _Float16* __restrict__ Wh,
                                                   float* __restrict__ biasN,
                                                   float* __restrict__ AB) {
    const int c = blockIdx.x;          // 0..255
    const int t = c >> 2, i = c & 3;
    const float* wsrc = p + t * PPT + i * KDIM;
    for (int k = threadIdx.x; k < KDIM; k += 128)
        Wh[c * KDIM + k] = (_Float16)wsrc[k];
    if (threadIdx.x == 0)
        biasN[c] = p[t * PPT + 7 * KDIM + i];
    if (threadIdx.x == 64 && c < 64) {
        const int tt = c;
        const float* lg = p + tt * PPT + 7 * 513;   // leaf logits, 8 x 2
        const float w = tw[tt];
        float ld[8][2];
#pragma unroll
        for (int j = 0; j < 8; ++j) {
            float a = lg[2 * j], b = lg[2 * j + 1];
            float m = fmaxf(a, b);
            float e0 = expf(a - m), e1 = expf(b - m);
            float s = e0 + e1;
            ld[j][0] = e0 / s; ld[j][1] = e1 / s;
        }
        float* o = AB + tt * 10;
#pragma unroll
        for (int cc = 0; cc < 2; ++cc) {
            o[0 + cc] = w * (ld[0][cc] + ld[2][cc] + ld[4][cc] + ld[6][cc]);
            o[2 + cc] = w * (ld[1][cc] - ld[2][cc]);
            o[4 + cc] = w * (ld[3][cc] - ld[4][cc]);
            o[6 + cc] = w * (ld[5][cc] - ld[6][cc]);
            o[8 + cc] = w * (ld[7][cc]);
        }
    }
}

// LDS map (38144 B / block, 4 blocks/CU):
//   xbuf: f16 [32 rows][512 k] = [32][64 granules of 16B] at 0 (32768 B)
//         granule swizzle: phys g' = g ^ (row & 15)
//   epilogue overlay (loop-dead): E f32 [32][260] at 0 (33280 B)
//   AB f32[640] at 33280 (2560 B);  P f32 [32][18] at 35840 (2304 B)
#define EPI_S 260
#define AB_OFF 33280
#define P_OFF 35840
#define P_S 18
#define LDS_BYTES 38144

__device__ __forceinline__ f16x8 cvt8(f32x4 a, f32x4 b) {
    f16x8 h;
    h[0] = (_Float16)a.x; h[1] = (_Float16)a.y; h[2] = (_Float16)a.z; h[3] = (_Float16)a.w;
    h[4] = (_Float16)b.x; h[5] = (_Float16)b.y; h[6] = (_Float16)b.z; h[7] = (_Float16)b.w;
    return h;
}

__global__ __launch_bounds__(256, 4) void main_kernel(const float* __restrict__ X,
                                                      const _Float16* __restrict__ Wh,
                                                      const float* __restrict__ biasN,
                                                      const float* __restrict__ ABg,
                                                      float* __restrict__ out) {
    extern __shared__ char smem[];
    const int tid = threadIdx.x;
    const int lane = tid & 63;
    const int wv = tid >> 6;         // wave 0..3 : owns cols wv*64 .. +63
    const int r15 = lane & 15;
    const int hi = lane >> 4;        // 0..3
    const int gr0 = blockIdx.x * 32; // 32 rows per block

    // AB coeffs -> LDS (region beyond the X buffer; no overlap)
    {
        float* abl = (float*)(smem + AB_OFF);
        for (int i = tid; i < 640; i += 256) abl[i] = ABg[i];
    }

    // ---- stage X[32][512] f32 -> f16 LDS, once, swizzled ----
    // thread owns row = tid>>3, granule range g = (tid&7)*8 .. +7 (64 k-values)
    {
        const int row = tid >> 3, q = tid & 7;
        const float* Xr = X + (size_t)(gr0 + row) * KDIM + q * 64;
        char* xb = smem + row * 1024;
#pragma unroll
        for (int j = 0; j < 8; ++j) {
            const int g = q * 8 + j;
            f32x4 a = __builtin_nontemporal_load((const f32x4*)(Xr + j * 8));
            f32x4 b = __builtin_nontemporal_load((const f32x4*)(Xr + j * 8 + 4));
            *(f16x8*)(xb + ((g ^ (row & 15)) << 4)) = cvt8(a, b);
        }
    }

    // W fragment base: col = wv*64 + ct*16 + r15, k-chunk = hi*8
    const _Float16* Wbase = Wh + (size_t)(wv * 64 + r15) * KDIM + hi * 8;

    f32x4 acc[2][4];
#pragma unroll
    for (int rt = 0; rt < 2; ++rt)
#pragma unroll
        for (int ct = 0; ct < 4; ++ct)
            acc[rt][ct] = (f32x4){0.f, 0.f, 0.f, 0.f};

    // preload W step 0 (global loads; independent of LDS staging)
    f16x8 Wf[2][4];
#pragma unroll
    for (int ct = 0; ct < 4; ++ct)
        Wf[0][ct] = *(const f16x8*)(Wbase + (size_t)ct * 16 * KDIM);

    __syncthreads();   // X panel staged; the ONLY barrier before the epilogue

    // A-frag constants: row = rt*16 + r15; phys granule = (s*4+hi) ^ r15
    const char* xb0 = smem + r15 * 1024;          // rt=0 row base
    const char* xb1 = smem + (16 + r15) * 1024;   // rt=1 row base

#pragma unroll
    for (int s = 0; s < 16; ++s) {
        // prefetch W(s+1) into the other ring slot (L1/L2-hot)
        if (s < 15) {
#pragma unroll
            for (int ct = 0; ct < 4; ++ct)
                Wf[(s + 1) & 1][ct] =
                    *(const f16x8*)(Wbase + (size_t)ct * 16 * KDIM + (s + 1) * 32);
        }
        const int go = (((s * 4 + hi) ^ r15) << 4);
        f16x8 a0 = *(const f16x8*)(xb0 + go);
        f16x8 a1 = *(const f16x8*)(xb1 + go);
#pragma unroll
        for (int ct = 0; ct < 4; ++ct) {
            acc[0][ct] = __builtin_amdgcn_mfma_f32_16x16x32_f16(a0, Wf[s & 1][ct], acc[0][ct], 0, 0, 0);
            acc[1][ct] = __builtin_amdgcn_mfma_f32_16x16x32_f16(a1, Wf[s & 1][ct], acc[1][ct], 0, 0, 0);
        }
    }

    // ---- epilogue ----
    __syncthreads();   // all LDS A-reads done before E overlays xbuf

    float bl[4];
#pragma unroll
    for (int ct = 0; ct < 4; ++ct) bl[ct] = biasN[wv * 64 + ct * 16 + r15];

    {
        float* Ef = (float*)smem;
#pragma unroll
        for (int rt = 0; rt < 2; ++rt)
#pragma unroll
            for (int ct = 0; ct < 4; ++ct) {
                const int col = wv * 64 + ct * 16 + r15;
#pragma unroll
                for (int reg = 0; reg < 4; ++reg) {
                    const int row = rt * 16 + hi * 4 + reg;
                    float z = acc[rt][ct][reg] + bl[ct];
                    Ef[row * EPI_S + col] = __builtin_amdgcn_rcpf(1.f + __expf(-z));
                }
            }
    }
    __syncthreads();
    {   // reduce: thread -> row = tid>>3 (32 rows), tree-group tg = tid&7 (8 trees)
        const float* Ef = (const float*)smem;
        const float* abl = (const float*)(smem + AB_OFF);
        float* Pf = (float*)(smem + P_OFF);
        const int row = tid >> 3, tg = tid & 7;
        float s0 = 0.f, s1 = 0.f;
#pragma unroll
        for (int j = 0; j < 8; ++j) {
            const int t = tg * 8 + ((j + tg) & 7);   // rotation spreads E banks
            float4 dv = *(const float4*)&Ef[row * EPI_S + t * 4];
            const float* abt = &abl[t * 10];
            float inv = __builtin_amdgcn_rcpf(4.f + dv.w + 1e-8f);
            s0 += (abt[0] + dv.x * abt[2] + dv.y * abt[4] + dv.z * abt[6] + dv.w * abt[8]) * inv;
            s1 += (abt[1] + dv.x * abt[3] + dv.y * abt[5] + dv.z * abt[7] + dv.w * abt[9]) * inv;
        }
        Pf[row * P_S + tg * 2 + 0] = s0;
        Pf[row * P_S + tg * 2 + 1] = s1;
    }
    __syncthreads();
    if (tid < 64) {
        const float* Pf = (const float*)(smem + P_OFF);
        const int row = tid >> 1, c = tid & 1;
        float s = 0.f;
#pragma unroll
        for (int tg = 0; tg < 8; ++tg) s += Pf[row * P_S + tg * 2 + c];
        out[(size_t)(gr0 + row) * 2 + c] = s;
    }
}

extern "C" void kernel_launch(void* const* d_in, const int* in_sizes, int n_in,
                              void* d_out, int out_size, void* d_ws, size_t ws_size,
                              hipStream_t stream) {
    const float* x  = (const float*)d_in[0];
    const float* tp = (const float*)d_in[1];
    const float* tw = (const float*)d_in[2];
    float* out = (float*)d_out;

    _Float16* Wh = (_Float16*)d_ws;
    float* biasN = (float*)((char*)d_ws + 262144);
    float* AB    = (float*)((char*)d_ws + 263168);

    (void)hipFuncSetAttribute((const void*)reinterpret_cast<const void*>(&main_kernel),
                              hipFuncAttributeMaxDynamicSharedMemorySize, LDS_BYTES);

    prep_kernel<<<256, 128, 0, stream>>>(tp, tw, Wh, biasN, AB);
    main_kernel<<<2048, 256, LDS_BYTES, stream>>>(x, Wh, biasN, AB, out);
}

// Round 9
// 48.566 us; speedup vs baseline: 2.5591x; 2.5591x over previous
//
#include <hip/hip_runtime.h>
#include <stdint.h>

// Soft decision-tree ensemble, collapsed to:
//   out[b,c] = sum_t ( A'[t,c] + sum_{k<4} d[b,t,k]*B'[t,k,c] ) / (4 + d[b,t,3] + 1e-8)
//   d[b,t,k] = sigmoid( X[b,:] . W[t,k,:] + bias[t,k] ),  nodes 0..3 only.
// GEMM 65536x512 @ 512x256, memory-bound on X (134 MB fp32 read once).
// R9 = R8's zero-barrier structure with the two flaws R8's counters exposed fixed:
//  (1) W pre-tiled by prep into FRAGMENT-LINEAR layout -> every K-loop W load is
//      base + lane*16 (coalesced, 1 line-set/instr, L2-hot, ring-3 prefetch).
//      R8's 64-line gathers (8x L1/L2 amplification, MSHR-bound) were the 121us.
//  (2) LDS slot map ((g&7)^row)&7: conflict-free for BOTH staging ds_writes
//      (quarter-wave varies g) and A-frag ds_reads (quarter-wave varies row).
// Block = 32 rows; X staged once (full K, f16); ONE barrier pre-loop; 4 blk/CU.

#define KDIM 512
#define PPT 3607

typedef _Float16 f16x8 __attribute__((ext_vector_type(8)));
typedef float f32x4 __attribute__((ext_vector_type(4)));

// ws layout (bytes):
//   [0, 262144)       Whf  : _Float16 frag table [4 wv][16 s][4 ct][64 lane][8]
//   [262144, 263168)  biasN: float[256]
//   [263168, 265728)  AB   : float[64][10]

__global__ __launch_bounds__(128) void prep_kernel(const float* __restrict__ p,
                                                   const float* __restrict__ tw,
                                                   _Float16* __restrict__ Whf,
                                                   float* __restrict__ biasN,
                                                   float* __restrict__ AB) {
    const int c = blockIdx.x;          // 0..255 : col = t*4 + node
    const int t = c >> 2, i = c & 3;
    const int wv = c >> 6, ct = (c >> 4) & 3, r15 = c & 15;
    const float* wsrc = p + t * PPT + i * KDIM;
    for (int k = threadIdx.x; k < KDIM; k += 128) {
        const int s = k >> 5, hi = (k >> 3) & 3, j = k & 7;
        const int lane = hi * 16 + r15;
        Whf[((((wv * 16 + s) * 4 + ct) * 64) + lane) * 8 + j] = (_Float16)wsrc[k];
    }
    if (threadIdx.x == 0)
        biasN[c] = p[t * PPT + 7 * KDIM + i];
    if (threadIdx.x == 64 && c < 64) {
        const int tt = c;
        const float* lg = p + tt * PPT + 7 * 513;   // leaf logits, 8 x 2
        const float w = tw[tt];
        float ld[8][2];
#pragma unroll
        for (int j = 0; j < 8; ++j) {
            float a = lg[2 * j], b = lg[2 * j + 1];
            float m = fmaxf(a, b);
            float e0 = expf(a - m), e1 = expf(b - m);
            float s = e0 + e1;
            ld[j][0] = e0 / s; ld[j][1] = e1 / s;
        }
        float* o = AB + tt * 10;
#pragma unroll
        for (int cc = 0; cc < 2; ++cc) {
            o[0 + cc] = w * (ld[0][cc] + ld[2][cc] + ld[4][cc] + ld[6][cc]);
            o[2 + cc] = w * (ld[1][cc] - ld[2][cc]);
            o[4 + cc] = w * (ld[3][cc] - ld[4][cc]);
            o[6 + cc] = w * (ld[5][cc] - ld[6][cc]);
            o[8 + cc] = w * (ld[7][cc]);
        }
    }
}

// LDS map (38144 B / block, 4 blocks/CU):
//   xbuf: f16 [32 rows][64 granules of 16B] at 0 (32768 B)
//         phys granule g' = ((g>>3)<<3) | (((g&7) ^ (row&7)) & 7)
//   epilogue overlay (loop-dead): E f32 [32][260] at 0 (33280 B)
//   AB f32[640] at 33280 (2560 B);  P f32 [32][18] at 35840 (2304 B)
#define EPI_S 260
#define AB_OFF 33280
#define P_OFF 35840
#define P_S 18
#define LDS_BYTES 38144

__device__ __forceinline__ f16x8 cvt8(f32x4 a, f32x4 b) {
    f16x8 h;
    h[0] = (_Float16)a.x; h[1] = (_Float16)a.y; h[2] = (_Float16)a.z; h[3] = (_Float16)a.w;
    h[4] = (_Float16)b.x; h[5] = (_Float16)b.y; h[6] = (_Float16)b.z; h[7] = (_Float16)b.w;
    return h;
}

__global__ __launch_bounds__(256, 4) void main_kernel(const float* __restrict__ X,
                                                      const _Float16* __restrict__ Whf,
                                                      const float* __restrict__ biasN,
                                                      const float* __restrict__ ABg,
                                                      float* __restrict__ out) {
    extern __shared__ char smem[];
    const int tid = threadIdx.x;
    const int lane = tid & 63;
    const int wv = tid >> 6;         // wave 0..3 : owns cols wv*64 .. +63
    const int r15 = lane & 15;
    const int hi = lane >> 4;        // 0..3
    const int gr0 = blockIdx.x * 32; // 32 rows per block

    // AB coeffs -> LDS (region beyond the X buffer; no overlap)
    {
        float* abl = (float*)(smem + AB_OFF);
        for (int i = tid; i < 640; i += 256) abl[i] = ABg[i];
    }

    // ---- stage X[32][512] f32 -> f16 LDS, once ----
    // instruction j: output granule c = j*256 + tid; global read = 32 B at c*32
    // (contiguous 2 KB per 64-lane instruction -> 16 lines, fully coalesced);
    // dest row = c>>6, g = c&63, phys slot varies with g&7 -> conflict-free write.
    {
        const float* Xpan = X + (size_t)gr0 * KDIM;
#pragma unroll
        for (int j = 0; j < 8; ++j) {
            const int c = j * 256 + tid;
            const int row = c >> 6, g = c & 63;
            f32x4 a = *(const f32x4*)(Xpan + (size_t)c * 8);
            f32x4 b = *(const f32x4*)(Xpan + (size_t)c * 8 + 4);
            const int gp = ((g >> 3) << 3) | (((g & 7) ^ row) & 7);
            *(f16x8*)(smem + row * 1024 + (gp << 4)) = cvt8(a, b);
        }
    }

    // ---- W fragment stream: coalesced loads from the pre-tiled table ----
    const _Float16* Wfp = Whf + (size_t)wv * 32768 + lane * 8;  // + (s*4+ct)*512

    f32x4 acc[2][4];
#pragma unroll
    for (int rt = 0; rt < 2; ++rt)
#pragma unroll
        for (int ct = 0; ct < 4; ++ct)
            acc[rt][ct] = (f32x4){0.f, 0.f, 0.f, 0.f};

    f16x8 Wf[3][4];
#pragma unroll
    for (int ct = 0; ct < 4; ++ct) {
        Wf[0][ct] = *(const f16x8*)(Wfp + (0 * 4 + ct) * 512);
        Wf[1][ct] = *(const f16x8*)(Wfp + (1 * 4 + ct) * 512);
    }

    __syncthreads();   // X panel staged; the ONLY barrier before the epilogue

    const char* xb0 = smem + r15 * 1024;          // A rows 0..15
    const char* xb1 = smem + (16 + r15) * 1024;   // A rows 16..31

#pragma unroll
    for (int s = 0; s < 16; ++s) {
        // prefetch W(s+2) (coalesced, L2-hot, 2 steps of latency slack)
        if (s <= 13) {
#pragma unroll
            for (int ct = 0; ct < 4; ++ct)
                Wf[(s + 2) % 3][ct] = *(const f16x8*)(Wfp + ((s + 2) * 4 + ct) * 512);
        }
        const int g = s * 4 + hi;
        const int gp = ((g >> 3) << 3) | (((g & 7) ^ r15) & 7);
        f16x8 a0 = *(const f16x8*)(xb0 + (gp << 4));
        f16x8 a1 = *(const f16x8*)(xb1 + (gp << 4));
#pragma unroll
        for (int ct = 0; ct < 4; ++ct) {
            acc[0][ct] = __builtin_amdgcn_mfma_f32_16x16x32_f16(a0, Wf[s % 3][ct], acc[0][ct], 0, 0, 0);
            acc[1][ct] = __builtin_amdgcn_mfma_f32_16x16x32_f16(a1, Wf[s % 3][ct], acc[1][ct], 0, 0, 0);
        }
    }

    // ---- epilogue (R8-verified) ----
    __syncthreads();   // all LDS A-reads done before E overlays xbuf

    float bl[4];
#pragma unroll
    for (int ct = 0; ct < 4; ++ct) bl[ct] = biasN[wv * 64 + ct * 16 + r15];

    {
        float* Ef = (float*)smem;
#pragma unroll
        for (int rt = 0; rt < 2; ++rt)
#pragma unroll
            for (int ct = 0; ct < 4; ++ct) {
                const int col = wv * 64 + ct * 16 + r15;
#pragma unroll
                for (int reg = 0; reg < 4; ++reg) {
                    const int row = rt * 16 + hi * 4 + reg;
                    float z = acc[rt][ct][reg] + bl[ct];
                    Ef[row * EPI_S + col] = __builtin_amdgcn_rcpf(1.f + __expf(-z));
                }
            }
    }
    __syncthreads();
    {   // reduce: thread -> row = tid>>3 (32 rows), tree-group tg = tid&7 (8 trees)
        const float* Ef = (const float*)smem;
        const float* abl = (const float*)(smem + AB_OFF);
        float* Pf = (float*)(smem + P_OFF);
        const int row = tid >> 3, tg = tid & 7;
        float s0 = 0.f, s1 = 0.f;
#pragma unroll
        for (int j = 0; j < 8; ++j) {
            const int t = tg * 8 + ((j + tg) & 7);   // rotation spreads E banks
            float4 dv = *(const float4*)&Ef[row * EPI_S + t * 4];
            const float* abt = &abl[t * 10];
            float inv = __builtin_amdgcn_rcpf(4.f + dv.w + 1e-8f);
            s0 += (abt[0] + dv.x * abt[2] + dv.y * abt[4] + dv.z * abt[6] + dv.w * abt[8]) * inv;
            s1 += (abt[1] + dv.x * abt[3] + dv.y * abt[5] + dv.z * abt[7] + dv.w * abt[9]) * inv;
        }
        Pf[row * P_S + tg * 2 + 0] = s0;
        Pf[row * P_S + tg * 2 + 1] = s1;
    }
    __syncthreads();
    if (tid < 64) {
        const float* Pf = (const float*)(smem + P_OFF);
        const int row = tid >> 1, c = tid & 1;
        float s = 0.f;
#pragma unroll
        for (int tg = 0; tg < 8; ++tg) s += Pf[row * P_S + tg * 2 + c];
        out[(size_t)(gr0 + row) * 2 + c] = s;
    }
}

extern "C" void kernel_launch(void* const* d_in, const int* in_sizes, int n_in,
                              void* d_out, int out_size, void* d_ws, size_t ws_size,
                              hipStream_t stream) {
    const float* x  = (const float*)d_in[0];
    const float* tp = (const float*)d_in[1];
    const float* tw = (const float*)d_in[2];
    float* out = (float*)d_out;

    _Float16* Whf = (_Float16*)d_ws;
    float* biasN = (float*)((char*)d_ws + 262144);
    float* AB    = (float*)((char*)d_ws + 263168);

    (void)hipFuncSetAttribute((const void*)reinterpret_cast<const void*>(&main_kernel),
                              hipFuncAttributeMaxDynamicSharedMemorySize, LDS_BYTES);

    prep_kernel<<<256, 128, 0, stream>>>(tp, tw, Whf, biasN, AB);
    main_kernel<<<2048, 256, LDS_BYTES, stream>>>(x, Whf, biasN, AB, out);
}

// Round 10
// 47.694 us; speedup vs baseline: 2.6059x; 1.0183x over previous
//
#include <hip/hip_runtime.h>
#include <stdint.h>

// Soft decision-tree ensemble, collapsed to:
//   out[b,c] = sum_t ( A'[t,c] + sum_{k<4} d[b,t,k]*B'[t,k,c] ) / (4 + d[b,t,3] + 1e-8)
//   d[b,t,k] = sigmoid( X[b,:] . W[t,k,:] + bias[t,k] ),  nodes 0..3 only.
// GEMM 65536x512 @ 512x256, memory-bound on X (134 MB fp32 read once).
// R10: X-ONLY traffic. 256 persistent blocks (1/CU, 8 waves). W in REGISTERS
// (128 VGPR/wave, one coalesced read of a fragment-linear table -> no re-fetch,
// no gather). X: 8 panels x 32 rows x K=512, contiguous 64KB reads, reg-hop ->
// f16 LDS dbuf. Epilogue fully in-register via DPP quad/row reductions (tree's
// 4 nodes sit on adjacent lanes) -> no E-matrix LDS round-trip; 2 barriers/panel.

#define KDIM 512
#define PPT 3607

typedef _Float16 f16x8 __attribute__((ext_vector_type(8)));
typedef float f32x4 __attribute__((ext_vector_type(4)));

// ws layout (bytes):
//   [0, 262144)       Whf  : _Float16 frag table [8 wv][16 s][2 ct][64 lane][8]
//   [262144, 263168)  biasN: float[256]
//   [263168, 265728)  AB   : float[64][10]  (A'c0,A'c1, B'n0c0.., w_t folded)

__global__ __launch_bounds__(128) void prep_kernel(const float* __restrict__ p,
                                                   const float* __restrict__ tw,
                                                   _Float16* __restrict__ Whf,
                                                   float* __restrict__ biasN,
                                                   float* __restrict__ AB) {
    const int c = blockIdx.x;          // 0..255 : col = t*4 + node
    const int t = c >> 2, i = c & 3;
    const int wv = c >> 5, ct = (c >> 4) & 1, r15 = c & 15;
    const float* wsrc = p + t * PPT + i * KDIM;
    for (int k = threadIdx.x; k < KDIM; k += 128) {
        const int s = k >> 5, hi = (k >> 3) & 3, j = k & 7;
        const int lane = hi * 16 + r15;
        Whf[((((wv * 16 + s) * 2 + ct) * 64) + lane) * 8 + j] = (_Float16)wsrc[k];
    }
    if (threadIdx.x == 0)
        biasN[c] = p[t * PPT + 7 * KDIM + i];
    if (threadIdx.x == 64 && c < 64) {
        const int tt = c;
        const float* lg = p + tt * PPT + 7 * 513;   // leaf logits, 8 x 2
        const float w = tw[tt];
        float ld[8][2];
#pragma unroll
        for (int j = 0; j < 8; ++j) {
            float a = lg[2 * j], b = lg[2 * j + 1];
            float m = fmaxf(a, b);
            float e0 = expf(a - m), e1 = expf(b - m);
            float s = e0 + e1;
            ld[j][0] = e0 / s; ld[j][1] = e1 / s;
        }
        float* o = AB + tt * 10;
#pragma unroll
        for (int cc = 0; cc < 2; ++cc) {
            o[0 + cc] = w * (ld[0][cc] + ld[2][cc] + ld[4][cc] + ld[6][cc]);
            o[2 + cc] = w * (ld[1][cc] - ld[2][cc]);
            o[4 + cc] = w * (ld[3][cc] - ld[4][cc]);
            o[6 + cc] = w * (ld[5][cc] - ld[6][cc]);
            o[8 + cc] = w * (ld[7][cc]);
        }
    }
}

// LDS (67584 B, 1 block/CU):
//   xbuf[2]: f16 [32 rows][64 granules of 16B] at b*32768
//            phys granule g' = (g&~7) | ((g ^ (row&7)) & 7)   (both sides use it)
//   P: float2 [32 rows][8 wv] at 65536 (2048 B)
#define XB_STRIDE 32768
#define P_OFF 65536
#define LDS_BYTES 67584

__device__ __forceinline__ f16x8 cvt8(float4 a, float4 b) {
    f16x8 h;
    h[0] = (_Float16)a.x; h[1] = (_Float16)a.y; h[2] = (_Float16)a.z; h[3] = (_Float16)a.w;
    h[4] = (_Float16)b.x; h[5] = (_Float16)b.y; h[6] = (_Float16)b.z; h[7] = (_Float16)b.w;
    return h;
}

template<int CTRL>
__device__ __forceinline__ float dpp_mov(float x) {
    return __builtin_bit_cast(float,
        __builtin_amdgcn_update_dpp(0, __builtin_bit_cast(int, x), CTRL, 0xF, 0xF, true));
}

__global__ __launch_bounds__(512, 2) void main_kernel(const float* __restrict__ X,
                                                      const _Float16* __restrict__ Whf,
                                                      const float* __restrict__ biasN,
                                                      const float* __restrict__ ABg,
                                                      float* __restrict__ out) {
    extern __shared__ char smem[];
    const int tid = threadIdx.x;
    const int lane = tid & 63;
    const int w = tid >> 6;          // wave 0..7 : owns cols w*32 .. +31
    const int r15 = lane & 15;
    const int hi = lane >> 4;        // 0..3
    const size_t gr0 = (size_t)blockIdx.x * 256;   // 256 rows per block

    // ---- W into registers (one coalesced pass over the fragment table) ----
    const _Float16* Wfp = Whf + (size_t)w * 16384 + (size_t)lane * 8;
    f16x8 Wf[16][2];
#pragma unroll
    for (int s = 0; s < 16; ++s)
#pragma unroll
        for (int ct = 0; ct < 2; ++ct)
            Wf[s][ct] = *(const f16x8*)(Wfp + (s * 2 + ct) * 512);

    // ---- per-lane epilogue constants ----
    const int k = r15 & 3;
    float A_[2][2], B_[2][2], bl[2];
#pragma unroll
    for (int ct = 0; ct < 2; ++ct) {
        const int t = w * 8 + ct * 4 + (r15 >> 2);
        A_[ct][0] = (k == 0) ? ABg[t * 10 + 0] : 0.f;
        A_[ct][1] = (k == 0) ? ABg[t * 10 + 1] : 0.f;
        B_[ct][0] = ABg[t * 10 + 2 + 2 * k + 0];
        B_[ct][1] = ABg[t * 10 + 2 + 2 * k + 1];
        bl[ct] = biasN[w * 32 + ct * 16 + r15];
    }

    // ---- X staging map: thread owns row = tid>>4, granules gb..gb+3 (gb=(tid&15)*4)
    const int srow = tid >> 4, sgb = (tid & 15) * 4;
    char* const nb_base = smem + srow * 1024;
    float2* const Pf = (float2*)(smem + P_OFF);

    float4 xr[8];
    // prologue: load panel 0, stage into xbuf0
    {
        const float* Xs = X + (gr0 + srow) * KDIM + sgb * 8;
#pragma unroll
        for (int i = 0; i < 8; ++i) xr[i] = *(const float4*)(Xs + i * 4);
#pragma unroll
        for (int j = 0; j < 4; ++j) {
            const int g = sgb + j;
            const int gp = (g & ~7) | ((g ^ (srow & 7)) & 7);
            *(f16x8*)(nb_base + (gp << 4)) = cvt8(xr[2 * j], xr[2 * j + 1]);
        }
    }
    asm volatile("s_waitcnt vmcnt(0) lgkmcnt(0)" ::: "memory");
    __builtin_amdgcn_s_barrier();

    for (int p = 0; p < 8; ++p) {
        // (1) issue next panel's global loads (in flight under compute+epilogue)
        if (p < 7) {
            const float* Xs = X + (gr0 + (p + 1) * 32 + srow) * KDIM + sgb * 8;
#pragma unroll
            for (int i = 0; i < 8; ++i) xr[i] = *(const float4*)(Xs + i * 4);
        }
        // (2) compute panel p from xbuf[p&1]
        f32x4 acc[2][2];
#pragma unroll
        for (int rt = 0; rt < 2; ++rt)
#pragma unroll
            for (int ct = 0; ct < 2; ++ct)
                acc[rt][ct] = (f32x4){0.f, 0.f, 0.f, 0.f};
        {
            const char* xb = smem + (p & 1) * XB_STRIDE;
#pragma unroll
            for (int s = 0; s < 16; ++s) {
                const int g0 = s * 4 + hi;
                const int go = ((g0 & ~7) | ((g0 ^ (r15 & 7)) & 7)) << 4;
                f16x8 a0 = *(const f16x8*)(xb + r15 * 1024 + go);
                f16x8 a1 = *(const f16x8*)(xb + (16 + r15) * 1024 + go);
                acc[0][0] = __builtin_amdgcn_mfma_f32_16x16x32_f16(a0, Wf[s][0], acc[0][0], 0, 0, 0);
                acc[0][1] = __builtin_amdgcn_mfma_f32_16x16x32_f16(a0, Wf[s][1], acc[0][1], 0, 0, 0);
                acc[1][0] = __builtin_amdgcn_mfma_f32_16x16x32_f16(a1, Wf[s][0], acc[1][0], 0, 0, 0);
                acc[1][1] = __builtin_amdgcn_mfma_f32_16x16x32_f16(a1, Wf[s][1], acc[1][1], 0, 0, 0);
            }
        }
        // (3) in-register epilogue: sigmoid + tree math + DPP reductions
        //     quad (4 lanes) = one tree's 4 nodes; row-of-16 = 4 trees; x2 ct = 8 trees/wave
#pragma unroll
        for (int rt = 0; rt < 2; ++rt)
#pragma unroll
            for (int reg = 0; reg < 4; ++reg) {
                float o0 = 0.f, o1 = 0.f;
#pragma unroll
                for (int ct = 0; ct < 2; ++ct) {
                    float z = acc[rt][ct][reg] + bl[ct];
                    float d = __builtin_amdgcn_rcpf(1.f + __expf(-z));
                    float v0 = fmaf(d, B_[ct][0], A_[ct][0]);
                    float v1 = fmaf(d, B_[ct][1], A_[ct][1]);
                    v0 += dpp_mov<0xB1>(v0); v0 += dpp_mov<0x4E>(v0);   // quad sum
                    v1 += dpp_mov<0xB1>(v1); v1 += dpp_mov<0x4E>(v1);
                    float d3 = dpp_mov<0xFF>(d);                        // quad bcast lane3
                    float inv = __builtin_amdgcn_rcpf(4.f + d3 + 1e-8f);
                    o0 = fmaf(v0, inv, o0);
                    o1 = fmaf(v1, inv, o1);
                }
                o0 += dpp_mov<0x124>(o0); o0 += dpp_mov<0x128>(o0);     // 4 quads in row16
                o1 += dpp_mov<0x124>(o1); o1 += dpp_mov<0x128>(o1);
                if (r15 == 0) {
                    const int row = rt * 16 + hi * 4 + reg;
                    Pf[row * 8 + w] = make_float2(o0, o1);
                }
            }
        asm volatile("s_waitcnt lgkmcnt(0)" ::: "memory");   // P writes visible
        __builtin_amdgcn_s_barrier();
        if (tid < 64) {
            const int row = tid >> 1, c = tid & 1;
            float s = 0.f;
#pragma unroll
            for (int g = 0; g < 8; ++g)
                s += ((const float*)Pf)[(row * 8 + g) * 2 + c];
            out[(gr0 + p * 32 + row) * 2 + c] = s;
        }
        // (4) stage next panel into xbuf[(p+1)&1] (its readers finished at the
        //     end-barrier of iteration p-1; we are past it)
        if (p < 7) {
            char* nb = nb_base + ((p + 1) & 1) * XB_STRIDE;
#pragma unroll
            for (int j = 0; j < 4; ++j) {
                const int g = sgb + j;
                const int gp = (g & ~7) | ((g ^ (srow & 7)) & 7);
                *(f16x8*)(nb + (gp << 4)) = cvt8(xr[2 * j], xr[2 * j + 1]);
            }
            // end-barrier: panel p+1 fully staged & visible; all waves done with xbuf[p&1]
            asm volatile("s_waitcnt vmcnt(0) lgkmcnt(0)" ::: "memory");
            __builtin_amdgcn_s_barrier();
        }
    }
}

extern "C" void kernel_launch(void* const* d_in, const int* in_sizes, int n_in,
                              void* d_out, int out_size, void* d_ws, size_t ws_size,
                              hipStream_t stream) {
    const float* x  = (const float*)d_in[0];
    const float* tp = (const float*)d_in[1];
    const float* tw = (const float*)d_in[2];
    float* out = (float*)d_out;

    _Float16* Whf = (_Float16*)d_ws;
    float* biasN = (float*)((char*)d_ws + 262144);
    float* AB    = (float*)((char*)d_ws + 263168);

    (void)hipFuncSetAttribute((const void*)reinterpret_cast<const void*>(&main_kernel),
                              hipFuncAttributeMaxDynamicSharedMemorySize, LDS_BYTES);

    prep_kernel<<<256, 128, 0, stream>>>(tp, tw, Whf, biasN, AB);
    main_kernel<<<256, 512, LDS_BYTES, stream>>>(x, Whf, biasN, AB, out);
}